// Round 2
// baseline (198.110 us; speedup 1.0000x reference)
//
#include <hip/hip_runtime.h>

typedef __bf16 bf16;
typedef __bf16 bf16x8 __attribute__((ext_vector_type(8), aligned(16)));
typedef float  f32x4  __attribute__((ext_vector_type(4)));

#define B_ 8
#define T_ 16
#define N_ 2048
#define C_ 512

// ---- small helpers ----
__device__ inline bf16x8 load8_f32(const float* p) {
    float4 a = *(const float4*)p;
    float4 b = *(const float4*)(p + 4);
    bf16x8 r;
    r[0] = (bf16)a.x; r[1] = (bf16)a.y; r[2] = (bf16)a.z; r[3] = (bf16)a.w;
    r[4] = (bf16)b.x; r[5] = (bf16)b.y; r[6] = (bf16)b.z; r[7] = (bf16)b.w;
    return r;
}

// out_scene[b][c] = mean_t vd_s[b][t][c]  -> d_out[b*1024 + c]   (fp32 in/out)
__global__ void k_scene(const float* __restrict__ vd_s, float* __restrict__ out) {
    int gt = blockIdx.x * 256 + threadIdx.x;      // 4096 threads
    int b = gt >> 9, c = gt & 511;
    float s = 0.f;
#pragma unroll
    for (int t = 0; t < T_; ++t) s += vd_s[(size_t)b * T_ * C_ + t * C_ + c];
    out[b * 2 * C_ + c] = s * (1.0f / T_);
}

// q[c] = sum_k b1[k] * W2[k][c]
__global__ void k_q(const float* __restrict__ b1, const float* __restrict__ W2,
                    float* __restrict__ q) {
    int c = blockIdx.x * 256 + threadIdx.x;       // 512 threads
    float s = 0.f;
    for (int k = 0; k < C_; ++k) s += b1[k] * W2[k * C_ + c];
    q[c] = s;
}

// Gt[c][k] = sum_m W2[m][c] * W1[m][k]   (= (W1^T W2) transposed), bf16 out
__global__ void k_gt(const float* __restrict__ W1, const float* __restrict__ W2,
                     bf16* __restrict__ Gt) {
    int k = blockIdx.x * 256 + threadIdx.x;       // coalesced over k
    int c = blockIdx.y;
    float s = 0.f;
    for (int m = 0; m < C_; ++m) s += W2[m * C_ + c] * W1[m * C_ + k];
    Gt[c * C_ + k] = (bf16)s;
}

// v[b][row] = dot(nodes[b][row][:], q)   one wave per row (fp32 nodes)
__global__ void k_v(const float* __restrict__ nodes, const float* __restrict__ q,
                    float* __restrict__ v) {
    int wid = threadIdx.x >> 6, lane = threadIdx.x & 63;
    int row = blockIdx.x * 4 + wid;
    int b = blockIdx.y;
    const float* p = nodes + (size_t)b * N_ * C_ + (size_t)row * C_ + lane * 8;
    float4 a = *(const float4*)p;
    float4 bb = *(const float4*)(p + 4);
    const float* qq = q + lane * 8;
    float s = a.x * qq[0] + a.y * qq[1] + a.z * qq[2] + a.w * qq[3]
            + bb.x * qq[4] + bb.y * qq[5] + bb.z * qq[6] + bb.w * qq[7];
#pragma unroll
    for (int m = 32; m; m >>= 1) s += __shfl_xor(s, m);
    if (lane == 0) v[b * N_ + row] = s;
}

// NT GEMM: C[z][m][n] (bf16) = sum_k A[z][m][k]*B[z][n][k] (+ bias[z][n]).
// A/B may be fp32 (converted to bf16 during staging) or bf16.
// 128x128 tile, BK=32, 4 waves (2x2), each wave 64x64 via 4x4 16x16x32 MFMA frags.
template <bool AF32, bool BF32>
__global__ __launch_bounds__(256) void gemm_nt(
    const void* __restrict__ A, size_t strideA,
    const void* __restrict__ Bm, size_t strideB,
    const float* __restrict__ bias, int biasStride,
    bf16* __restrict__ C, size_t strideC,
    int N, int K) {
    __shared__ __attribute__((aligned(16))) bf16 lA[128 * 32];
    __shared__ __attribute__((aligned(16))) bf16 lB[128 * 32];
    const int tid = threadIdx.x;
    const int lane = tid & 63, wid = tid >> 6;
    const int wm = wid >> 1, wn = wid & 1;
    const int z = blockIdx.z;
    const int bm = blockIdx.x * 128, bn = blockIdx.y * 128;

    f32x4 acc[4][4];
#pragma unroll
    for (int i = 0; i < 4; ++i)
#pragma unroll
        for (int j = 0; j < 4; ++j) acc[i][j] = f32x4{0.f, 0.f, 0.f, 0.f};

    const int nkt = K >> 5;
    for (int kt = 0; kt < nkt; ++kt) {
        bf16x8 va[2], vb[2];
#pragma unroll
        for (int r = 0; r < 2; ++r) {
            int ca = tid + 256 * r;          // chunk id: row = ca>>2, 16B quarter = ca&3
            int row = ca >> 2, qd = ca & 3;
            size_t offA = (size_t)z * strideA + (size_t)(bm + row) * K + kt * 32 + qd * 8;
            size_t offB = (size_t)z * strideB + (size_t)(bn + row) * K + kt * 32 + qd * 8;
            if constexpr (AF32) va[r] = load8_f32((const float*)A + offA);
            else                va[r] = *(const bf16x8*)((const bf16*)A + offA);
            if constexpr (BF32) vb[r] = load8_f32((const float*)Bm + offB);
            else                vb[r] = *(const bf16x8*)((const bf16*)Bm + offB);
        }
        __syncthreads();                      // prev iter's frag reads done
#pragma unroll
        for (int r = 0; r < 2; ++r) {
            int ca = tid + 256 * r;
            *(bf16x8*)&lA[ca * 8] = va[r];
            *(bf16x8*)&lB[ca * 8] = vb[r];
        }
        __syncthreads();
        bf16x8 af[4], bfr[4];
#pragma unroll
        for (int i = 0; i < 4; ++i)
            af[i] = *(const bf16x8*)&lA[(wm * 64 + i * 16 + (lane & 15)) * 32 + (lane >> 4) * 8];
#pragma unroll
        for (int j = 0; j < 4; ++j)
            bfr[j] = *(const bf16x8*)&lB[(wn * 64 + j * 16 + (lane & 15)) * 32 + (lane >> 4) * 8];
#pragma unroll
        for (int i = 0; i < 4; ++i)
#pragma unroll
            for (int j = 0; j < 4; ++j)
                acc[i][j] = __builtin_amdgcn_mfma_f32_16x16x32_bf16(af[i], bfr[j], acc[i][j], 0, 0, 0);
    }

    const float* biasb = bias ? bias + (size_t)z * biasStride : nullptr;
    bf16* Cb = C + (size_t)z * strideC;
#pragma unroll
    for (int i = 0; i < 4; ++i) {
#pragma unroll
        for (int j = 0; j < 4; ++j) {
            int col = bn + wn * 64 + j * 16 + (lane & 15);
            float bv = biasb ? biasb[col] : 0.f;
#pragma unroll
            for (int r = 0; r < 4; ++r) {
                int row = bm + wm * 64 + i * 16 + (lane >> 4) * 4 + r;
                Cb[(size_t)row * N + col] = (bf16)(acc[i][j][r] + bv);
            }
        }
    }
}

// Row-softmax of a 16x2048 strip of adj (bf16); accumulate column sums into w[b][:].
__global__ __launch_bounds__(256) void k_softmax_w(const bf16* __restrict__ adj,
                                                   float* __restrict__ w) {
    __shared__ __attribute__((aligned(16))) bf16 strip[16 * 2048];   // 64KB
    const int tid = threadIdx.x;
    const int b = blockIdx.y, rb = blockIdx.x;
    const bf16* src = adj + (size_t)b * N_ * N_ + (size_t)rb * 16 * N_;
#pragma unroll
    for (int i = 0; i < 16; ++i) {
        int c = i * 256 + tid;
        ((bf16x8*)strip)[c] = ((const bf16x8*)src)[c];
    }
    __syncthreads();
    const int row = tid >> 4, s = tid & 15;   // 16 threads per row
    bf16x8 rv[16];
#pragma unroll
    for (int i = 0; i < 16; ++i)
        rv[i] = *(const bf16x8*)&strip[row * 2048 + (s + 16 * i) * 8];
    float m = -3.4e38f;
#pragma unroll
    for (int i = 0; i < 16; ++i)
#pragma unroll
        for (int e = 0; e < 8; ++e) m = fmaxf(m, (float)rv[i][e]);
#pragma unroll
    for (int msk = 8; msk; msk >>= 1) m = fmaxf(m, __shfl_xor(m, msk));
    float l = 0.f;
#pragma unroll
    for (int i = 0; i < 16; ++i)
#pragma unroll
        for (int e = 0; e < 8; ++e) l += __expf((float)rv[i][e] - m);
#pragma unroll
    for (int msk = 8; msk; msk >>= 1) l += __shfl_xor(l, msk);
    float rinv = 1.0f / l;
#pragma unroll
    for (int i = 0; i < 16; ++i) {
        bf16x8 ev;
#pragma unroll
        for (int e = 0; e < 8; ++e) ev[e] = (bf16)(__expf((float)rv[i][e] - m) * rinv);
        *(bf16x8*)&strip[row * 2048 + (s + 16 * i) * 8] = ev;
    }
    __syncthreads();
    float* wb = w + b * N_;
#pragma unroll
    for (int jc = 0; jc < 8; ++jc) {
        int j = jc * 256 + tid;
        float sum = 0.f;
#pragma unroll
        for (int r = 0; r < 16; ++r) sum += (float)strip[r * 2048 + j];
        atomicAdd(&wb[j], sum);
    }
}

// gpacc[b][c] += sum_j (w[b][j]+1) * nodes[b][j][c]   over a 128-row slab (fp32 nodes)
__global__ void k_gp(const float* __restrict__ nodes, const float* __restrict__ w,
                     float* __restrict__ gpacc) {
    int c = blockIdx.y * 256 + threadIdx.x;
    int b = blockIdx.z;
    int j0 = blockIdx.x * 128;
    const float* nb = nodes + (size_t)b * N_ * C_;
    const float* wb = w + b * N_;
    float acc = 0.f;
    for (int j = 0; j < 128; ++j) {
        float wj = wb[j0 + j] + 1.0f;
        acc += wj * nb[(size_t)(j0 + j) * C_ + c];
    }
    atomicAdd(&gpacc[b * C_ + c], acc);
}

__global__ void k_fin(const float* __restrict__ gpacc, float* __restrict__ out) {
    int gt = blockIdx.x * 256 + threadIdx.x;      // 4096 threads
    int b = gt >> 9, c = gt & 511;
    out[b * 2 * C_ + C_ + c] = gpacc[b * C_ + c] * (1.0f / N_);
}

extern "C" void kernel_launch(void* const* d_in, const int* in_sizes, int n_in,
                              void* d_out, int out_size, void* d_ws, size_t ws_size,
                              hipStream_t stream) {
    const float* vd_s  = (const float*)d_in[0];
    const float* nodes = (const float*)d_in[1];
    const float* W1    = (const float*)d_in[2];
    const float* b1    = (const float*)d_in[3];
    const float* W2    = (const float*)d_in[4];
    // d_in[5] (b2) adds a row-constant to adj -> cancels in row-softmax -> unused
    float* out = (float*)d_out;

    char* ws = (char*)d_ws;
    bf16*  H     = (bf16*)(ws);                               // 8x2048x512  bf16 = 16MB
    bf16*  adj   = (bf16*)(ws + ((size_t)16 << 20));          // 8x2048x2048 bf16 = 64MB
    bf16*  Gt    = (bf16*)(ws + ((size_t)80 << 20));          // 512x512 bf16 = 512KB
    float* q     = (float*)(ws + ((size_t)80 << 20) + (512u << 10));           // 2KB
    float* v     = (float*)(ws + ((size_t)80 << 20) + (512u << 10) + 4096);    // 64KB
    float* w     = (float*)(ws + ((size_t)80 << 20) + (512u << 10) + 4096 + 65536);
    float* gpacc = (float*)(ws + ((size_t)80 << 20) + (512u << 10) + 4096 + 65536 + 65536);

    (void)hipMemsetAsync(w, 0, 65536 + 16384, stream);        // zero w + gpacc

    k_scene<<<16, 256, 0, stream>>>(vd_s, out);
    k_q<<<2, 256, 0, stream>>>(b1, W2, q);
    k_gt<<<dim3(2, 512), 256, 0, stream>>>(W1, W2, Gt);
    k_v<<<dim3(512, 8), 256, 0, stream>>>(nodes, q, v);

    // H[b] = nodes[b] @ Gt^T   (M=2048, N=512, K=512)  A=fp32, B=bf16
    gemm_nt<true, false><<<dim3(16, 4, 8), 256, 0, stream>>>(
        nodes, (size_t)N_ * C_, Gt, (size_t)0, nullptr, 0,
        H, (size_t)N_ * C_, C_, C_);
    // adj[b] = H[b] @ nodes[b]^T + v[b][col]   (M=2048, N=2048, K=512)  A=bf16, B=fp32
    gemm_nt<false, true><<<dim3(16, 16, 8), 256, 0, stream>>>(
        H, (size_t)N_ * C_, nodes, (size_t)N_ * C_, v, N_,
        adj, (size_t)N_ * N_, N_, C_);

    k_softmax_w<<<dim3(128, 8), 256, 0, stream>>>(adj, w);
    k_gp<<<dim3(16, 2, 8), 256, 0, stream>>>(nodes, w, gpacc);
    k_fin<<<16, 256, 0, stream>>>(gpacc, out);
}

// Round 3
// 139.682 us; speedup vs baseline: 1.4183x; 1.4183x over previous
//
#include <hip/hip_runtime.h>

typedef __bf16 bf16;
typedef __bf16 bf16x8 __attribute__((ext_vector_type(8), aligned(16)));
typedef float  f32x4  __attribute__((ext_vector_type(4)));

#define B_ 8
#define T_ 16
#define N_ 2048
#define C_ 512

// ---- helpers ----
__device__ inline bf16x8 load8_f32(const float* p) {
    float4 a = *(const float4*)p;
    float4 b = *(const float4*)(p + 4);
    bf16x8 r;
    r[0] = (bf16)a.x; r[1] = (bf16)a.y; r[2] = (bf16)a.z; r[3] = (bf16)a.w;
    r[4] = (bf16)b.x; r[5] = (bf16)b.y; r[6] = (bf16)b.z; r[7] = (bf16)b.w;
    return r;
}

__device__ inline void gload_lds16(const bf16* g, bf16* l) {
    __builtin_amdgcn_global_load_lds(
        (const __attribute__((address_space(1))) void*)g,
        (__attribute__((address_space(3))) void*)l, 16, 0, 0);
}

// out_scene[b][c] = mean_t vd_s[b][t][c]  (fp32 in/out)
__global__ void k_scene(const float* __restrict__ vd_s, float* __restrict__ out) {
    int gt = blockIdx.x * 256 + threadIdx.x;
    int b = gt >> 9, c = gt & 511;
    float s = 0.f;
#pragma unroll
    for (int t = 0; t < T_; ++t) s += vd_s[(size_t)b * T_ * C_ + t * C_ + c];
    out[b * 2 * C_ + c] = s * (1.0f / T_);
}

// fp32 -> bf16 bulk convert (16 elems/thread)
__global__ void k_cvt(const float* __restrict__ in, bf16* __restrict__ out) {
    size_t i = ((size_t)blockIdx.x * 256 + threadIdx.x) * 16;
    *(bf16x8*)(out + i)     = load8_f32(in + i);
    *(bf16x8*)(out + i + 8) = load8_f32(in + i + 8);
}

// 512x512 transpose + convert: Wt[c][k] = W[k][c]
__global__ void k_wt(const float* __restrict__ W, bf16* __restrict__ Wt) {
    __shared__ float t[32][33];
    int bx = blockIdx.x * 32, by = blockIdx.y * 32;
    int tx = threadIdx.x & 31, ty = threadIdx.x >> 5;
#pragma unroll
    for (int r = 0; r < 32; r += 8)
        t[ty + r][tx] = W[(size_t)(by + ty + r) * C_ + bx + tx];
    __syncthreads();
#pragma unroll
    for (int r = 0; r < 32; r += 8)
        Wt[(size_t)(bx + ty + r) * C_ + by + tx] = (bf16)t[tx][ty + r];
}

// q[c] = sum_k b1[k] * W2t[c][k]   one wave per c
__global__ void k_q(const float* __restrict__ b1, const bf16* __restrict__ W2t,
                    float* __restrict__ q) {
    int wid = threadIdx.x >> 6, lane = threadIdx.x & 63;
    int c = blockIdx.x * 4 + wid;
    bf16x8 v8 = *(const bf16x8*)(W2t + (size_t)c * C_ + lane * 8);
    float s = 0.f;
#pragma unroll
    for (int i = 0; i < 8; ++i) s += (float)v8[i] * b1[lane * 8 + i];
#pragma unroll
    for (int m = 32; m; m >>= 1) s += __shfl_xor(s, m);
    if (lane == 0) q[c] = s;
}

// Batched NT GEMM, all bf16: C[z][m][n] = sum_k A[z][m][k]*B[z][n][k] (+ bias[n]).
// 128x128 tile, BK=64, global_load_lds staging, XOR-swizzled LDS.
__global__ __launch_bounds__(256) void gemm_nt(
    const bf16* __restrict__ A, size_t strideA,
    const bf16* __restrict__ Bm, size_t strideB,
    const float* __restrict__ bias,
    bf16* __restrict__ C, size_t strideC,
    int N, int K) {
    __shared__ __attribute__((aligned(16))) bf16 lA[128 * 64];
    __shared__ __attribute__((aligned(16))) bf16 lB[128 * 64];
    const int tid = threadIdx.x;
    const int lane = tid & 63, w = tid >> 6;
    const int wm = w >> 1, wn = w & 1;
    const int z = blockIdx.z;
    const int bm = blockIdx.x * 128, bn = blockIdx.y * 128;
    const bf16* Ab = A + (size_t)z * strideA;
    const bf16* Bb = Bm + (size_t)z * strideB;

    f32x4 acc[4][4];
#pragma unroll
    for (int i = 0; i < 4; ++i)
#pragma unroll
        for (int j = 0; j < 4; ++j) acc[i][j] = f32x4{0.f, 0.f, 0.f, 0.f};

    const int nkt = K >> 6;
    for (int kt = 0; kt < nkt; ++kt) {
        // stage 128x64 A and B tiles. chunk ca = c*256+tid; row=ca>>3; physical
        // 16B slot (ca&7) holds global chunk (ca&7)^(row&7)  [rule #21: linear
        // LDS dest + inverse-swizzled global src]
#pragma unroll
        for (int c = 0; c < 4; ++c) {
            int ca = c * 256 + tid;
            int row = ca >> 3;
            int qd = (ca & 7) ^ (row & 7);
            gload_lds16(Ab + (size_t)(bm + row) * K + kt * 64 + qd * 8,
                        lA + c * 2048 + w * 512);
            gload_lds16(Bb + (size_t)(bn + row) * K + kt * 64 + qd * 8,
                        lB + c * 2048 + w * 512);
        }
        __syncthreads();   // compiler drains vmcnt(0) before barrier

        bf16x8 af[2][4], bfr[2][4];
#pragma unroll
        for (int ks = 0; ks < 2; ++ks) {
            int y = ks * 4 + (lane >> 4);   // logical 16B chunk within row
#pragma unroll
            for (int i = 0; i < 4; ++i) {
                int ra = wm * 64 + i * 16 + (lane & 15);
                int rb = wn * 64 + i * 16 + (lane & 15);
                af[ks][i]  = *(const bf16x8*)&lA[ra * 64 + ((y ^ (ra & 7)) * 8)];
                bfr[ks][i] = *(const bf16x8*)&lB[rb * 64 + ((y ^ (rb & 7)) * 8)];
            }
        }
#pragma unroll
        for (int ks = 0; ks < 2; ++ks)
#pragma unroll
            for (int i = 0; i < 4; ++i)
#pragma unroll
                for (int j = 0; j < 4; ++j)
                    acc[i][j] = __builtin_amdgcn_mfma_f32_16x16x32_bf16(
                        af[ks][i], bfr[ks][j], acc[i][j], 0, 0, 0);
        __syncthreads();   // LDS reuse next iter
    }

    bf16* Cb = C + (size_t)z * strideC;
#pragma unroll
    for (int i = 0; i < 4; ++i) {
#pragma unroll
        for (int j = 0; j < 4; ++j) {
            int col = bn + wn * 64 + j * 16 + (lane & 15);
            float bv = bias ? bias[col] : 0.f;
#pragma unroll
            for (int r = 0; r < 4; ++r) {
                int row = bm + wm * 64 + i * 16 + (lane >> 4) * 4 + r;
                Cb[(size_t)row * N + col] = (bf16)(acc[i][j][r] + bv);
            }
        }
    }
}

// Row-softmax of a 16x2048 strip of adj (bf16); accumulate column sums into w[b][:].
__global__ __launch_bounds__(256) void k_softmax_w(const bf16* __restrict__ adj,
                                                   float* __restrict__ w) {
    __shared__ __attribute__((aligned(16))) bf16 strip[16 * 2048];   // 64KB
    const int tid = threadIdx.x;
    const int b = blockIdx.y, rb = blockIdx.x;
    const bf16* src = adj + (size_t)b * N_ * N_ + (size_t)rb * 16 * N_;
#pragma unroll
    for (int i = 0; i < 16; ++i) {
        int c = i * 256 + tid;
        ((bf16x8*)strip)[c] = ((const bf16x8*)src)[c];
    }
    __syncthreads();
    const int row = tid >> 4, s = tid & 15;   // 16 threads per row
    bf16x8 rv[16];
#pragma unroll
    for (int i = 0; i < 16; ++i)
        rv[i] = *(const bf16x8*)&strip[row * 2048 + (s + 16 * i) * 8];
    float m = -3.4e38f;
#pragma unroll
    for (int i = 0; i < 16; ++i)
#pragma unroll
        for (int e = 0; e < 8; ++e) m = fmaxf(m, (float)rv[i][e]);
#pragma unroll
    for (int msk = 8; msk; msk >>= 1) m = fmaxf(m, __shfl_xor(m, msk));
    float l = 0.f;
#pragma unroll
    for (int i = 0; i < 16; ++i)
#pragma unroll
        for (int e = 0; e < 8; ++e) l += __expf((float)rv[i][e] - m);
#pragma unroll
    for (int msk = 8; msk; msk >>= 1) l += __shfl_xor(l, msk);
    float rinv = 1.0f / l;
#pragma unroll
    for (int i = 0; i < 16; ++i) {
        bf16x8 ev;
#pragma unroll
        for (int e = 0; e < 8; ++e) ev[e] = (bf16)(__expf((float)rv[i][e] - m) * rinv);
        *(bf16x8*)&strip[row * 2048 + (s + 16 * i) * 8] = ev;
    }
    __syncthreads();
    float* wb = w + b * N_;
#pragma unroll
    for (int jc = 0; jc < 8; ++jc) {
        int j = jc * 256 + tid;
        float sum = 0.f;
#pragma unroll
        for (int r = 0; r < 16; ++r) sum += (float)strip[r * 2048 + j];
        atomicAdd(&wb[j], sum);
    }
}

// gpacc[b][c] += sum_j (w[b][j]+1) * nodes[b][j][c]   over a 128-row slab (fp32 nodes)
__global__ void k_gp(const float* __restrict__ nodes, const float* __restrict__ w,
                     float* __restrict__ gpacc) {
    int c = blockIdx.y * 256 + threadIdx.x;
    int b = blockIdx.z;
    int j0 = blockIdx.x * 128;
    const float* nb = nodes + (size_t)b * N_ * C_;
    const float* wb = w + b * N_;
    float acc = 0.f;
    for (int j = 0; j < 128; ++j) {
        float wj = wb[j0 + j] + 1.0f;
        acc += wj * nb[(size_t)(j0 + j) * C_ + c];
    }
    atomicAdd(&gpacc[b * C_ + c], acc);
}

__global__ void k_fin(const float* __restrict__ gpacc, float* __restrict__ out) {
    int gt = blockIdx.x * 256 + threadIdx.x;
    int b = gt >> 9, c = gt & 511;
    out[b * 2 * C_ + C_ + c] = gpacc[b * C_ + c] * (1.0f / N_);
}

extern "C" void kernel_launch(void* const* d_in, const int* in_sizes, int n_in,
                              void* d_out, int out_size, void* d_ws, size_t ws_size,
                              hipStream_t stream) {
    const float* vd_s  = (const float*)d_in[0];
    const float* nodes = (const float*)d_in[1];
    const float* W1    = (const float*)d_in[2];
    const float* b1    = (const float*)d_in[3];
    const float* W2    = (const float*)d_in[4];
    // d_in[5] (b2) adds a row-constant to adj -> cancels in row-softmax -> unused
    float* out = (float*)d_out;

    char* ws = (char*)d_ws;
    bf16*  nodes_bf = (bf16*)(ws);                                  // 16 MB
    bf16*  H2       = (bf16*)(ws + ((size_t)16 << 20));             // 16 MB
    bf16*  adj      = (bf16*)(ws + ((size_t)32 << 20));             // 64 MB
    bf16*  W1t      = (bf16*)(ws + ((size_t)96 << 20));             // 512 KB
    bf16*  W2t      = (bf16*)(ws + ((size_t)96 << 20) + (512u << 10));
    bf16*  Gt       = (bf16*)(ws + ((size_t)96 << 20) + (1024u << 10));
    float* q        = (float*)(ws + ((size_t)96 << 20) + (1536u << 10));       // 2 KB
    float* w        = (float*)(ws + ((size_t)96 << 20) + (1536u << 10) + 4096);
    float* gpacc    = (float*)(ws + ((size_t)96 << 20) + (1536u << 10) + 4096 + 65536);

    (void)hipMemsetAsync(w, 0, 65536 + 16384, stream);   // zero w + gpacc

    k_scene<<<16, 256, 0, stream>>>(vd_s, out);
    k_cvt<<<2048, 256, 0, stream>>>(nodes, nodes_bf);    // 8*2048*512/16
    k_wt<<<dim3(16, 16), 256, 0, stream>>>(W1, W1t);
    k_wt<<<dim3(16, 16), 256, 0, stream>>>(W2, W2t);
    k_q<<<128, 256, 0, stream>>>(b1, W2t, q);

    // Gt[c][k] = sum_m W2t[c][m]*W1t[k][m]   (M=N=K=512, single batch)
    gemm_nt<<<dim3(4, 4, 1), 256, 0, stream>>>(
        W2t, 0, W1t, 0, nullptr, Gt, 0, C_, C_);
    // H2[b] = nodes_bf[b] @ Gt^T + q[col]   (M=2048, N=512, K=512)
    gemm_nt<<<dim3(16, 4, 8), 256, 0, stream>>>(
        nodes_bf, (size_t)N_ * C_, Gt, 0, q,
        H2, (size_t)N_ * C_, C_, C_);
    // adj[b] = H2[b] @ nodes_bf[b]^T   (M=2048, N=2048, K=512)
    gemm_nt<<<dim3(16, 16, 8), 256, 0, stream>>>(
        H2, (size_t)N_ * C_, nodes_bf, (size_t)N_ * C_, nullptr,
        adj, (size_t)N_ * N_, N_, C_);

    k_softmax_w<<<dim3(128, 8), 256, 0, stream>>>(adj, w);
    k_gp<<<dim3(16, 2, 8), 256, 0, stream>>>(nodes, w, gpacc);
    k_fin<<<16, 256, 0, stream>>>(gpacc, out);
}